// Round 10
// baseline (567.044 us; speedup 1.0000x reference)
//
#include <hip/hip_runtime.h>
#include <hip/hip_bf16.h>
#include <cstdint>

#define B_   16
#define N_   1369
#define NP   1536
#define D_   1024
#define NQK  2048
#define SLD  1568   // S leading dim (3136B rows: odd multiple of 64B)
#define QLD  2080   // QK leading dim (4160B rows: odd multiple of 64B)

typedef __bf16 bf16x8_t __attribute__((ext_vector_type(8)));
typedef __bf16 bf16x4_t __attribute__((ext_vector_type(4)));
typedef float  f32x4_t  __attribute__((ext_vector_type(4)));

__device__ __forceinline__ float  bf2f(__bf16 x) { return (float)x; }
__device__ __forceinline__ __bf16 f2bf(float x)  { return (__bf16)x; }

#define GLOAD_LDS16(g, l) __builtin_amdgcn_global_load_lds( \
    (const __attribute__((address_space(1))) void*)(g),     \
    (__attribute__((address_space(3))) void*)(l), 16, 0, 0)

// ---------------------------------------------------------------- pos table
__global__ __launch_bounds__(256)
void pos_kernel(float* __restrict__ pos)
{
    const int idx = blockIdx.x * 256 + threadIdx.x;
    if (idx >= N_ * D_) return;
    const int n = idx >> 10, f = idx & 1023;
    const int row = n / 37, col = n - row * 37;
    const float base = (f < 512) ? (float)row : (float)col;
    const int  t2   = (f & 511) >> 1;
    const float dv  = __expf(-0.03597789207803197f * (float)t2);
    const float ang = base * dv;
    pos[idx] = (f & 1) ? cosf(ang) : sinf(ang);
}

// ----------------------------------------------- x = patch + pos, cast bf16
__global__ __launch_bounds__(256)
void addpos_kernel(const float* __restrict__ patch, const float* __restrict__ pos,
                   __bf16* __restrict__ X)
{
    const long tid = (long)blockIdx.x * 256 + threadIdx.x;
    const long e   = tid * 4;
    const int  f   = (int)(e & 1023);
    const long nb  = e >> 10;
    const int  n   = (int)(nb % NP);
    const long b   = nb / NP;
    bf16x4_t o;
    if (n < N_) {
        const float4 p = *(const float4*)(patch + ((b * N_ + n) << 10) + f);
        const float4 q = *(const float4*)(pos + ((long)n << 10) + f);
        o[0] = f2bf(p.x + q.x); o[1] = f2bf(p.y + q.y);
        o[2] = f2bf(p.z + q.z); o[3] = f2bf(p.w + q.w);
    } else {
        o[0] = o[1] = o[2] = o[3] = f2bf(0.f);
    }
    *(bf16x4_t*)(X + e) = o;
}

// ---------------------------------- W[i][o] -> WT[o][i] bf16 (Wq, Wk only)
__global__ __launch_bounds__(256)
void wcast_kernel(const float* __restrict__ W0, const float* __restrict__ W1,
                  __bf16* __restrict__ T0, __bf16* __restrict__ T1)
{
    const float* W = blockIdx.z == 0 ? W0 : W1;
    __bf16*      T = blockIdx.z == 0 ? T0 : T1;
    __shared__ float tile[64][65];
    const int o0 = blockIdx.x * 64, i0 = blockIdx.y * 64;
    const int t = threadIdx.x;
    const int tr = t >> 4, tc = (t & 15) * 4;
    #pragma unroll
    for (int rr = 0; rr < 64; rr += 16) {
        float4 v = *(const float4*)(W + (long)(i0 + rr + tr) * 1024 + o0 + tc);
        tile[rr + tr][tc + 0] = v.x; tile[rr + tr][tc + 1] = v.y;
        tile[rr + tr][tc + 2] = v.z; tile[rr + tr][tc + 3] = v.w;
    }
    __syncthreads();
    #pragma unroll
    for (int rr = 0; rr < 64; rr += 16) {
        bf16x4_t o;
        o[0] = f2bf(tile[tc + 0][rr + tr]); o[1] = f2bf(tile[tc + 1][rr + tr]);
        o[2] = f2bf(tile[tc + 2][rr + tr]); o[3] = f2bf(tile[tc + 3][rr + tr]);
        *(bf16x4_t*)(T + (long)(o0 + rr + tr) * 1024 + i0 + tc) = o;
    }
}

// ------------------------------------------------- bias concat [bq|bk] 2048
__global__ __launch_bounds__(256)
void bcat_kernel(const float* __restrict__ bq, const float* __restrict__ bk,
                 float* __restrict__ bcat)
{
    const int i = blockIdx.x * 256 + threadIdx.x;
    if (i >= NQK) return;
    bcat[i] = (i < 1024) ? bq[i] : bk[i - 1024];
}

// ---------------- 256^2 GEMM body, BK=32, 16 waves (4x4), 64 KiB LDS dbuf
// 2 blocks/CU (LDS 2x64KB <= 160KB, 32 waves/CU): one block's vmcnt+barrier
// drain overlaps the other block's MFMA (m114 mechanism) -- the 128KB/1-block
// variants (r2-r8) were stuck at 38-42% MfmaUtil in lockstep.
// Swizzle algebra identical to r8-proven (group stride 512 elems):
//   elem (R,k) at (R>>4)*512 + (R&15)*32 + ((k&31) ^ ((R&8)?16:0)).
// STATS=1 (scores): M=0 softmax (|S|max ~9 << 88, no overflow);
// per-row Z partial via 4-hop shfl + one atomicAdd -> rowZ.
template<int HAS_BIAS, int STATS>
__device__ __forceinline__
void gemm_body(const __bf16* __restrict__ A, const __bf16* __restrict__ Bt,
               __bf16* __restrict__ C, const float* __restrict__ bias,
               float* __restrict__ rowZ,
               int lda, int ldb, int ldc, int Kd, float scale,
               long sA, long sB, long sC, int tilesN, int tilesPerBatch, int cpx)
{
    __shared__ __bf16 lds[32768];   // 64 KiB: buf c at c*16384 (A +0, B +8192)
    const int bid = blockIdx.x;
    const int vt  = (bid & 7) * cpx + (bid >> 3);      // XCD-bijective (nwg%8==0)
    const int bz  = vt / tilesPerBatch;
    const int rem = vt - bz * tilesPerBatch;
    const int ty  = rem / tilesN;
    const int tx  = rem - ty * tilesN;
    A  += (long)bz * sA;  Bt += (long)bz * sB;  C += (long)bz * sC;
    const int m0 = ty * 256, n0 = tx * 256;

    const int t  = threadIdx.x;
    const int w  = t >> 6, l = t & 63;
    const int wr = w >> 2, wc = w & 3;         // 4 x 4 wave grid
    const int lr = l & 15, lh = l >> 4;

    // swizzled ds_read lane offset (elems), group stride 32/row
    const int laneF  = lr * 32 + ((lh * 8) ^ (((lr >> 3) & 1) << 4));
    // staging (16 waves, 1 gload per matrix per tile): wave w -> rowgroup w;
    // lane l -> row_local l>>2, k (l&3)*8, swizzle XOR when row_local>=8.
    const int rstage = w * 16 + (l >> 2);
    const int kstage = ((l & 3) * 8) ^ (((l >> 5) & 1) << 4);

    const __bf16* Ag = A  + (long)(m0 + rstage) * lda + kstage;
    const __bf16* Bg = Bt + (long)(n0 + rstage) * ldb + kstage;
    __bf16* dA = lds + w * 512;
    __bf16* dB = lds + 8192 + w * 512;

#define SA_(buf, kt) GLOAD_LDS16(Ag + (kt) * 32, dA + (buf) * 16384)
#define SB_(buf, kt) GLOAD_LDS16(Bg + (kt) * 32, dB + (buf) * 16384)

    f32x4_t acc[4][4] = {};

    const int NT = Kd >> 5;                    // 32 K-tiles of 32
    SA_(0, 0); SB_(0, 0);
    asm volatile("s_waitcnt vmcnt(0)" ::: "memory");
    __builtin_amdgcn_s_barrier();

    for (int tk = 0; tk < NT; ++tk) {
        const int c = tk & 1, o = c ^ 1;
        if (tk + 1 < NT) { SA_(o, tk + 1); SB_(o, tk + 1); }
        const int cb = c * 16384;
        const __bf16* ap = lds + cb + wr * 2048 + laneF;
        const __bf16* bp = lds + cb + 8192 + wc * 2048 + laneF;
        bf16x8_t af[4], bfm[4];
        #pragma unroll
        for (int nn = 0; nn < 4; ++nn) bfm[nn] = *(const bf16x8_t*)(bp + nn * 512);
        #pragma unroll
        for (int mi = 0; mi < 4; ++mi) af[mi]  = *(const bf16x8_t*)(ap + mi * 512);
        __builtin_amdgcn_s_setprio(1);
        #pragma unroll
        for (int mi = 0; mi < 4; ++mi)
            #pragma unroll
            for (int nn = 0; nn < 4; ++nn)
                acc[mi][nn] = __builtin_amdgcn_mfma_f32_16x16x32_bf16(af[mi], bfm[nn], acc[mi][nn], 0, 0, 0);
        __builtin_amdgcn_s_setprio(0);
        asm volatile("s_waitcnt vmcnt(0)" ::: "memory");
        __builtin_amdgcn_s_barrier();
    }

    // epilogue: C/D layout col=lane&15, row=(lane>>4)*4+reg
    #pragma unroll
    for (int mi = 0; mi < 4; ++mi) {
        const int row = m0 + wr * 64 + mi * 16 + lh * 4;
        #pragma unroll
        for (int nn = 0; nn < 4; ++nn) {
            const int col = n0 + wc * 64 + nn * 16 + lr;
            const float bb = HAS_BIAS ? bias[col] : 0.0f;
            #pragma unroll
            for (int q = 0; q < 4; ++q) {
                if (!STATS || ((row + q) < N_ && col < N_))
                    C[(long)(row + q) * ldc + col] = f2bf(acc[mi][nn][q] * scale + bb);
            }
        }
    }

    if (STATS) {
        // per-row sum of exp(S) over this block's valid cols (M=0 softmax)
        #pragma unroll
        for (int mi = 0; mi < 4; ++mi) {
            #pragma unroll
            for (int qq = 0; qq < 4; ++qq) {
                float z = 0.f;
                #pragma unroll
                for (int nn = 0; nn < 4; ++nn) {
                    const int col = n0 + wc * 64 + nn * 16 + lr;
                    const float vr = bf2f(f2bf(acc[mi][nn][qq] * scale)); // == stored S
                    if (col < N_) z += __expf(vr);
                }
                #pragma unroll
                for (int o2 = 1; o2 <= 8; o2 <<= 1) z += __shfl_xor(z, o2);
                const int r = ty * 256 + wr * 64 + mi * 16 + lh * 4 + qq;
                if (lr == 0 && r < N_)
                    atomicAdd(rowZ + (long)bz * NP + r, z);
            }
        }
    }
#undef SA_
#undef SB_
}

// named instantiations so rocprof disambiguates the two GEMMs
__global__ __launch_bounds__(1024, 4)
void gemm_qk(const __bf16* A, const __bf16* Bt, __bf16* C, const float* bias,
             int lda, int ldb, int ldc, int Kd,
             int tilesN, int tilesPerBatch, int cpx)
{
    gemm_body<1, 0>(A, Bt, C, bias, nullptr, lda, ldb, ldc, Kd, 1.0f,
                    0, 0, 0, tilesN, tilesPerBatch, cpx);
}

__global__ __launch_bounds__(1024, 4)
void gemm_sc(const __bf16* A, const __bf16* Bt, __bf16* C, float* rowZ,
             int lda, int ldb, int ldc, int Kd, float scale,
             long sA, long sB, long sC, int tilesN, int tilesPerBatch, int cpx)
{
    gemm_body<0, 1>(A, Bt, C, nullptr, rowZ, lda, ldb, ldc, Kd, scale,
                    sA, sB, sC, tilesN, tilesPerBatch, cpx);
}

// ---- weighted column sums over attn = exp(S)/Z_q (M=0 softmax fused)
template<int WEIGHTED>
__global__ __launch_bounds__(256)
void colsum_kernel(const __bf16* __restrict__ attn, const float* __restrict__ rowZ,
                   const float* __restrict__ wv, float* __restrict__ out)
{
    const int t  = threadIdx.x;
    const int b  = blockIdx.y;
    const int q0 = blockIdx.x * 16;
    __shared__ float sZi[16];
    if (t < 16) {
        const int q = q0 + t;
        float wq = 0.f;
        if (q < N_) {
            wq = 1.f / rowZ[(long)b * NP + q];
            if (WEIGHTED) wq *= wv[b * NP + q];
        }
        sZi[t] = wq;
    }
    __syncthreads();
    const int k8 = t * 8;
    if (k8 < N_) {
        const int q1 = (q0 + 16 < N_) ? q0 + 16 : N_;
        float s[8] = {};
        const __bf16* base = attn + (long)b * NP * SLD + k8;
        for (int q = q0; q < q1; ++q) {
            bf16x8_t v = *(const bf16x8_t*)(base + (long)q * SLD);
            const float wq = sZi[q - q0];
            #pragma unroll
            for (int i = 0; i < 8; ++i) s[i] += wq * __expf(bf2f(v[i]));
        }
        #pragma unroll
        for (int i = 0; i < 8; ++i) atomicAdd(out + b * NP + k8 + i, s[i]);
    }
}

// ------------------- pa -> normalize -> curiosity modulation -> fa (output)
__global__ __launch_bounds__(256)
void fa_kernel(const float* __restrict__ pa_raw, const float* __restrict__ curiosity,
               const float* __restrict__ Wc1, const float* __restrict__ bc1,
               const float* __restrict__ Wc2, const float* __restrict__ bc2,
               const float* __restrict__ aw_p,
               float* __restrict__ fa_ws, float* __restrict__ out_fa)
{
    const int b = blockIdx.x, t = threadIdx.x;
    __shared__ float hsh[64];
    __shared__ float red[8];
    __shared__ float cwsh;
    if (t < 64) hsh[t] = fmaxf(0.f, curiosity[b] * Wc1[t] + bc1[t]);
    __syncthreads();
    if (t < 8) {
        float a = bc2[t];
        for (int j = 0; j < 64; ++j) a += hsh[j] * Wc2[j * 8 + t];
        red[t] = 1.f / (1.f + __expf(-a));
    }
    __syncthreads();
    if (t == 0) {
        float cw = 0.f;
        for (int i = 0; i < 8; ++i) cw += red[i];
        cwsh = cw * 0.125f;
    }
    __syncthreads();
    const float aw   = aw_p[0];
    const float modf = 1.f + aw * cwsh;
    const float sig  = 37.f / 6.f;
    const float inv2s2 = 1.f / (2.f * sig * sig);
    float pv[6];
    float s1 = 0.f;
    #pragma unroll
    for (int i = 0; i < 6; ++i) {
        const int k = t + i * 256;
        float p = 0.f;
        if (k < N_) {
            const int y = k / 37, x = k - y * 37;
            const float d2 = (float)((x - 18) * (x - 18) + (y - 18) * (y - 18));
            const float cb = 0.3f * __expf(-d2 * inv2s2);
            p = pa_raw[b * NP + k] * (1.f / 1369.f) + cb;
        }
        pv[i] = p; s1 += p;
    }
    #pragma unroll
    for (int o = 32; o; o >>= 1) s1 += __shfl_xor(s1, o);
    __syncthreads();
    if (!(t & 63)) red[t >> 6] = s1;
    __syncthreads();
    s1 = red[0] + red[1] + red[2] + red[3];
    const float inv1 = 1.f / (s1 + 1e-8f);
    float s2 = 0.f;
    #pragma unroll
    for (int i = 0; i < 6; ++i) {
        const int k = t + i * 256;
        if (k < N_) {
            const float f = fmaxf(pv[i] * inv1 * modf, 1e-8f);
            pv[i] = f; s2 += f;
        }
    }
    #pragma unroll
    for (int o = 32; o; o >>= 1) s2 += __shfl_xor(s2, o);
    if (!(t & 63)) red[4 + (t >> 6)] = s2;
    __syncthreads();
    s2 = red[4] + red[5] + red[6] + red[7];
    const float inv2 = 1.f / (s2 + 1e-8f);
    #pragma unroll
    for (int i = 0; i < 6; ++i) {
        const int k = t + i * 256;
        if (k < N_) {
            const float f = pv[i] * inv2;
            fa_ws[b * NP + k]  = f;
            out_fa[b * N_ + k] = f;
        }
    }
}

// ---------------- u[b][d] = sum_k g[b,k]*X[b,k,d]  (+ gsum[b] = sum_k g)
__global__ __launch_bounds__(256)
void u_kernel(const float* __restrict__ g, const __bf16* __restrict__ X,
              float* __restrict__ u, float* __restrict__ gsum)
{
    const int b  = blockIdx.y;
    const int k0 = blockIdx.x * 86;
    const int k1 = (k0 + 86 < N_) ? k0 + 86 : N_;
    const int d  = threadIdx.x * 4;
    float a0 = 0, a1 = 0, a2 = 0, a3 = 0, gs = 0;
    const __bf16* xb = X + (long)b * NP * D_ + d;
    for (int k = k0; k < k1; ++k) {
        const float gv = g[b * NP + k];
        bf16x4_t xv = *(const bf16x4_t*)(xb + (long)k * D_);
        a0 += gv * bf2f(xv[0]); a1 += gv * bf2f(xv[1]);
        a2 += gv * bf2f(xv[2]); a3 += gv * bf2f(xv[3]);
        gs += gv;
    }
    atomicAdd(u + b * D_ + d + 0, a0);
    atomicAdd(u + b * D_ + d + 1, a1);
    atomicAdd(u + b * D_ + d + 2, a2);
    atomicAdd(u + b * D_ + d + 3, a3);
    if (threadIdx.x == 0) atomicAdd(gsum + b, gs);
}

// ---------------- weighted[b][d] = u[b]@Wv[:,d] + gsum[b]*bv[d]  (fp32 GEMV)
__global__ __launch_bounds__(256)
void wv_gemv_kernel(const float* __restrict__ u, const float* __restrict__ gsum,
                    const float* __restrict__ Wv, const float* __restrict__ bv,
                    float* __restrict__ wout)
{
    const int dcx = blockIdx.x, b = blockIdx.y;
    const int t = threadIdx.x;
    __shared__ float us[1024];
    #pragma unroll
    for (int i = 0; i < 4; ++i) us[t + i * 256] = u[b * D_ + t + i * 256];
    __syncthreads();
    const int d = dcx * 256 + t;
    float a = gsum[b] * bv[d];
    #pragma unroll 8
    for (int i = 0; i < 1024; ++i) a += us[i] * Wv[(long)i * 1024 + d];
    wout[b * D_ + d] = a;
}

// ---------------- focal stage 1: h[b][j] = relu(weighted@Wp1+bp1), split-K
__global__ __launch_bounds__(256)
void focal1_kernel(const float* __restrict__ weighted, const float* __restrict__ Wp1,
                   const float* __restrict__ bp1, float* __restrict__ h)
{
    const int b = blockIdx.y, jc = blockIdx.x;
    const int t = threadIdx.x;
    const int jl = t >> 2, part = t & 3;
    const int j = jc * 64 + jl;
    const float* wb = weighted + b * 1024 + part * 256;
    const float* wp = Wp1 + (long)(part * 256) * 512 + j;
    float a = 0.f;
    #pragma unroll 8
    for (int d = 0; d < 256; ++d) a += wb[d] * wp[(long)d * 512];
    a += __shfl_xor(a, 1);
    a += __shfl_xor(a, 2);
    if (part == 0) h[b * 512 + j] = fmaxf(a + bp1[j], 0.f);
}

// ---------------- focal stage 2: out = h@Wp2 + bp2 (coalesced Wp2 rows)
__global__ __launch_bounds__(128)
void focal2_kernel(const float* __restrict__ h, const float* __restrict__ Wp2,
                   const float* __restrict__ bp2, float* __restrict__ out)
{
    const int b = blockIdx.x, o = threadIdx.x;
    __shared__ float hs[512];
    for (int i = o; i < 512; i += 128) hs[i] = h[b * 512 + i];
    __syncthreads();
    float a = bp2[o];
    #pragma unroll 8
    for (int j = 0; j < 512; ++j) a += hs[j] * Wp2[j * 128 + o];
    out[b * 128 + o] = a;
}

// ---------------------------------------------------------------- launcher
extern "C" void kernel_launch(void* const* d_in, const int* in_sizes, int n_in,
                              void* d_out, int out_size, void* d_ws, size_t ws_size,
                              hipStream_t stream)
{
    const float* patch     = (const float*)d_in[0];
    const float* curiosity = (const float*)d_in[1];
    const float* Wq  = (const float*)d_in[2];
    const float* bq  = (const float*)d_in[3];
    const float* Wk  = (const float*)d_in[4];
    const float* bk  = (const float*)d_in[5];
    const float* Wv  = (const float*)d_in[6];
    const float* bv  = (const float*)d_in[7];
    const float* Wc1 = (const float*)d_in[8];
    const float* bc1 = (const float*)d_in[9];
    const float* Wc2 = (const float*)d_in[10];
    const float* bc2 = (const float*)d_in[11];
    const float* Wp1 = (const float*)d_in[12];
    const float* bp1 = (const float*)d_in[13];
    const float* Wp2 = (const float*)d_in[14];
    const float* bp2 = (const float*)d_in[15];
    const float* aw  = (const float*)d_in[16];
    float* out = (float*)d_out;

    char* ws = (char*)d_ws;
    size_t off = 0;
    auto alloc = [&](size_t bytes) -> char* {
        char* p = ws + off;
        off += (bytes + 255) & ~(size_t)255;
        return p;
    };
    float*  pos  = (float*) alloc((size_t)N_ * D_ * 4);                 // 5.6 MB
    __bf16* X    = (__bf16*)alloc((size_t)B_ * NP * D_ * 2);            // 50.3 MB (alive to end)
    __bf16* WT   = (__bf16*)alloc((size_t)2 * D_ * D_ * 2);             // 4.2 MB
    __bf16* S    = (__bf16*)alloc((size_t)B_ * NP * SLD * 2);           // 77.1 MB
    __bf16* QK   = (__bf16*)alloc((size_t)B_ * NP * QLD * 2);           // 102.2 MB
    // zero-init region (single memset): pa | gbuf | ubuf | gsum | rowZ
    float*  pa   = (float*) alloc((size_t)B_ * NP * 4);
    float*  gbuf = (float*) alloc((size_t)B_ * NP * 4);
    float*  ubuf = (float*) alloc((size_t)B_ * D_ * 4);
    float*  gsum = (float*) alloc((size_t)B_ * 4);
    float*  rowZ = (float*) alloc((size_t)B_ * NP * 4);
    const size_t zbytes = (size_t)((char*)(rowZ + B_ * NP) - (char*)pa);
    float*  faw  = (float*) alloc((size_t)B_ * NP * 4);
    float*  bcat = (float*) alloc((size_t)NQK * 4);
    float*  hbuf = (float*) alloc((size_t)B_ * 512 * 4);
    float*  wsum = (float*) alloc((size_t)B_ * D_ * 4);

    (void)hipMemsetAsync(pa, 0, zbytes, stream);

    pos_kernel<<<(N_ * D_ + 255) / 256, 256, 0, stream>>>(pos);
    addpos_kernel<<<(int)((size_t)B_ * NP * D_ / 4 / 256), 256, 0, stream>>>(patch, pos, X);
    {
        dim3 g(16, 16, 2);
        wcast_kernel<<<g, 256, 0, stream>>>(Wq, Wk, WT, WT + D_ * D_);
    }
    bcat_kernel<<<(NQK + 255) / 256, 256, 0, stream>>>(bq, bk, bcat);
    {
        // QK projection: M=B*NP=24576(96), N=2048(8), K=1024 -> 768 blocks
        const int nwg = 96 * 8;
        gemm_qk<<<nwg, 1024, 0, stream>>>(X, WT, QK, bcat,
                                          D_, D_, QLD, D_, 8, nwg, nwg / 8);
    }
    {
        // scores: per batch M=N=1536(6x6), K=1024; 16 batches -> 576 blocks
        const int nwg = 36 * B_;
        gemm_sc<<<nwg, 1024, 0, stream>>>(QK, QK + 1024, S, rowZ,
                                          QLD, QLD, SLD, D_,
                                          0.08838834764831845f,
                                          (long)NP * QLD, (long)NP * QLD,
                                          (long)NP * SLD, 6, 36, nwg / 8);
    }
    {
        dim3 g(86, B_);
        colsum_kernel<0><<<g, 256, 0, stream>>>(S, rowZ, nullptr, pa);
    }
    fa_kernel<<<B_, 256, 0, stream>>>(pa, curiosity, Wc1, bc1, Wc2, bc2, aw,
                                      faw, out + B_ * 128);
    {
        dim3 g(86, B_);
        colsum_kernel<1><<<g, 256, 0, stream>>>(S, rowZ, faw, gbuf);
    }
    {
        dim3 g(16, B_);
        u_kernel<<<g, 256, 0, stream>>>(gbuf, X, ubuf, gsum);
    }
    {
        dim3 g(4, B_);
        wv_gemv_kernel<<<g, 256, 0, stream>>>(ubuf, gsum, Wv, bv, wsum);
    }
    {
        dim3 g(8, B_);
        focal1_kernel<<<g, 256, 0, stream>>>(wsum, Wp1, bp1, hbuf);
    }
    focal2_kernel<<<B_, 128, 0, stream>>>(hbuf, Wp2, bp2, out);
}